// Round 5
// baseline (1250.836 us; speedup 1.0000x reference)
//
#include <hip/hip_runtime.h>
#include <math.h>

#define BB 2
#define NN 100
#define TT 15
#define FF 6
#define KK 4
#define HH 128
#define EE 9900      // N*(N-1)
#define EPN 99       // edges per receiver (N-1)
#define NSTEP 14     // T-1
#define TILE_E 32

// ---------------------------------------------------------------------------
// K0: one-time init. hidden=0, agg4=0, Hs = hidden@W1_s = 0, Hr = hidden@W1_r + b1 = b1.
// grid: 400 blocks x 256 (covers B*N*K*H = 102400 = K*B*N*H)
// ---------------------------------------------------------------------------
__global__ __launch_bounds__(256) void k_init(
    const float* __restrict__ b1,   // [K,H]
    float* __restrict__ hidden,     // [B,N,H]
    float* __restrict__ agg4,       // [K,B,N,H]
    float* __restrict__ Hs,         // [B,N,K,H]
    float* __restrict__ Hr)         // [B,N,K,H]
{
    int i = blockIdx.x * 256 + threadIdx.x;      // < 102400
    if (i < BB * NN * HH) hidden[i] = 0.f;
    agg4[i] = 0.f;
    int k  = (i >> 7) & 3;
    int hh = i & 127;
    Hs[i] = 0.f;
    Hr[i] = b1[k * HH + hh];
}

// ---------------------------------------------------------------------------
// K2: edge messages for ONE edge type k (blockIdx.z) and a tile of 32 edges:
//   m1 = tanh(Hs[send] + Hr[recv])           (b1 already folded into Hr)
//   m2 = tanh(m1 @ W2[k] + b2[k])
//   acc = rel_type[b,e,k] * m2 / (K*F)
//   block-reduce over edge rows, then few atomics into agg4[k]
// grid: (ceil(E/TILE_E)=310, B, K), 256 threads
// ---------------------------------------------------------------------------
__global__ __launch_bounds__(256) void k_edge(
    const float* __restrict__ Hs,        // [B,N,K,H]
    const float* __restrict__ Hr,        // [B,N,K,H]
    const float* __restrict__ W2,        // [K,H,H]
    const float* __restrict__ b2,        // [K,H]
    const float* __restrict__ rel_type,  // [B,E,K]
    float* __restrict__ agg4)            // [K,B,N,H] atomic accum
{
    const int tile = blockIdx.x;
    const int b    = blockIdx.y;
    const int k    = blockIdx.z;
    const int e0   = tile * TILE_E;
    const int t    = threadIdx.x;
    const int tx   = t & 31;        // output h group
    const int ty   = t >> 5;        // 0..7 edge row
    const int h0   = tx * 4;

    __shared__ float m1[TILE_E][HH];     // 16 KB
    __shared__ float w2c[32][HH];        // 16 KB (reused as 8x128 reduction buf)
    __shared__ int   s_send[TILE_E], s_recv[TILE_E];

    if (t < TILE_E) {
        int e = e0 + t;
        if (e >= EE) e = EE - 1;
        int r = e / EPN;
        int j = e - r * EPN;
        s_recv[t] = r;
        s_send[t] = j + (j >= r ? 1 : 0);
    }
    __syncthreads();

    // this thread's 4 edges
    int  eidx[4], erecv[4];
    bool evalid[4];
#pragma unroll
    for (int ei = 0; ei < 4; ++ei) {
        int el = ty + 8 * ei;
        int e  = e0 + el;
        evalid[ei] = (e < EE);
        if (e >= EE) e = EE - 1;
        eidx[ei]  = e;
        erecv[ei] = s_recv[el];
    }

    // build m1 tile for this k: 4096 elems, 16 per thread
#pragma unroll
    for (int rep = 0; rep < 16; ++rep) {
        int idx = rep * 256 + t;
        int el  = idx >> 7;
        int hh  = idx & 127;
        int s   = s_send[el];
        int r   = s_recv[el];
        float v = Hs[((b * NN + s) * KK + k) * HH + hh]
                + Hr[((b * NN + r) * KK + k) * HH + hh];
        m1[el][hh] = tanhf(v);
    }

    float macc[4][4] = {};
    for (int jc = 0; jc < 4; ++jc) {
        __syncthreads();   // m1 visible (jc==0) / prev chunk GEMM done (jc>0)
        // stage W2[k] rows [jc*32, jc*32+32)
#pragma unroll
        for (int rep = 0; rep < 16; ++rep) {
            int idx = rep * 256 + t;
            int row = idx >> 7;
            int hh  = idx & 127;
            w2c[row][hh] = W2[(k * HH + jc * 32 + row) * HH + hh];
        }
        __syncthreads();
#pragma unroll
        for (int jq = 0; jq < 8; ++jq) {
            float4 w[4];
#pragma unroll
            for (int jj = 0; jj < 4; ++jj)
                w[jj] = *(const float4*)&w2c[jq * 4 + jj][h0];
#pragma unroll
            for (int ei = 0; ei < 4; ++ei) {
                int el = ty + 8 * ei;
                float4 mv = *(const float4*)&m1[el][jc * 32 + jq * 4];
                macc[ei][0] = fmaf(mv.x, w[0].x, fmaf(mv.y, w[1].x,
                              fmaf(mv.z, w[2].x, fmaf(mv.w, w[3].x, macc[ei][0]))));
                macc[ei][1] = fmaf(mv.x, w[0].y, fmaf(mv.y, w[1].y,
                              fmaf(mv.z, w[2].y, fmaf(mv.w, w[3].y, macc[ei][1]))));
                macc[ei][2] = fmaf(mv.x, w[0].z, fmaf(mv.y, w[1].z,
                              fmaf(mv.z, w[2].z, fmaf(mv.w, w[3].z, macc[ei][2]))));
                macc[ei][3] = fmaf(mv.x, w[0].w, fmaf(mv.y, w[1].w,
                              fmaf(mv.z, w[2].w, fmaf(mv.w, w[3].w, macc[ei][3]))));
            }
        }
    }

    // epilogue: tanh + b2, weight by rel_type and 1/(K*F)
    const float scale = 1.0f / (KK * FF);
    float acc[4][4];
#pragma unroll
    for (int ei = 0; ei < 4; ++ei) {
        float rt = rel_type[(b * EE + eidx[ei]) * KK + k] * scale;
#pragma unroll
        for (int hi = 0; hi < 4; ++hi) {
            float m2v = tanhf(macc[ei][hi] + b2[k * HH + h0 + hi]);
            acc[ei][hi] = rt * m2v;
        }
    }

    // ---- block-level reduction over the 8 edge rows, then few atomics ----
    // a 32-consecutive-edge tile spans at most 2 receivers (99 edges/receiver)
    const int rA = s_recv[0];
    const int rB = s_recv[TILE_E - 1];
    float sumA[4] = {0.f, 0.f, 0.f, 0.f};
    float sumB[4] = {0.f, 0.f, 0.f, 0.f};
#pragma unroll
    for (int ei = 0; ei < 4; ++ei) {
        if (!evalid[ei]) continue;
        if (erecv[ei] == rA) {
#pragma unroll
            for (int hi = 0; hi < 4; ++hi) sumA[hi] += acc[ei][hi];
        } else {
#pragma unroll
            for (int hi = 0; hi < 4; ++hi) sumB[hi] += acc[ei][hi];
        }
    }
    float* red = &w2c[0][0];          // reuse as [8][128]
    float* aggk = agg4 + ((size_t)k * BB + b) * NN * HH;
    __syncthreads();                  // GEMM reads of w2c complete
    *(float4*)&red[ty * HH + h0] = make_float4(sumA[0], sumA[1], sumA[2], sumA[3]);
    __syncthreads();
    if (ty == 0) {
#pragma unroll
        for (int hi = 0; hi < 4; ++hi) {
            float s = 0.f;
#pragma unroll
            for (int y = 0; y < 8; ++y) s += red[y * HH + h0 + hi];
            atomicAdd(&aggk[rA * HH + h0 + hi], s);
        }
    }
    if (rB != rA) {                   // block-uniform condition
        __syncthreads();
        *(float4*)&red[ty * HH + h0] = make_float4(sumB[0], sumB[1], sumB[2], sumB[3]);
        __syncthreads();
        if (ty == 0) {
#pragma unroll
            for (int hi = 0; hi < 4; ++hi) {
                float s = 0.f;
#pragma unroll
                for (int y = 0; y < 8; ++y) s += red[y * HH + h0 + hi];
                atomicAdd(&aggk[rB * HH + h0 + hi], s);
            }
        }
    }
}

// ---------------------------------------------------------------------------
// K3: GRU update + output MLP for one (b,n), then next-step node projections:
//   Hs = h_new @ W1[:,0:H,:],  Hr = h_new @ W1[:,H:2H,:] + b1
// Reads agg = sum_k agg4[k], then zeroes agg4 for the next step.
// grid: B*N blocks, 128 threads
// ---------------------------------------------------------------------------
__global__ __launch_bounds__(128) void k_gru_out(
    const float* __restrict__ data,   // [B,N,T,F]
    float* __restrict__ agg4,         // [K,B,N,H] read then zeroed
    float* __restrict__ hidden,       // [B,N,H] updated in place
    const float* __restrict__ W1,  const float* __restrict__ b1,
    const float* __restrict__ Whr, const float* __restrict__ Whi,
    const float* __restrict__ Whh,
    const float* __restrict__ Wir, const float* __restrict__ bir,
    const float* __restrict__ Wii, const float* __restrict__ bii,
    const float* __restrict__ Win, const float* __restrict__ bin_,
    const float* __restrict__ Wo1, const float* __restrict__ bo1,
    const float* __restrict__ Wo2, const float* __restrict__ bo2,
    const float* __restrict__ Wo3, const float* __restrict__ bo3,
    float* __restrict__ Hs,           // [B,N,K,H] for next step
    float* __restrict__ Hr,           // [B,N,K,H]
    float* __restrict__ out,          // [B,N,NSTEP,F]
    const int* __restrict__ ps_ptr, int step)
{
    const int bn = blockIdx.x;
    const int t  = threadIdx.x;   // 0..127

    __shared__ float sa[HH];
    __shared__ float sh[HH];
    __shared__ float p1[HH];
    __shared__ float p2[HH];
    __shared__ float ins[FF];

    {
        float s = 0.f;
#pragma unroll
        for (int k = 0; k < KK; ++k) {
            size_t idx = ((size_t)k * BB * NN + bn) * HH + t;
            s += agg4[idx];
            agg4[idx] = 0.f;          // zero for next step (own element: no race)
        }
        sa[t] = s;
    }
    if (t < FF) {
        int ps = ps_ptr[0];
        bool use_gt = (ps <= 1) || (step % ps == 0);
        int prev = (step > 0) ? (step - 1) : 0;   // in-bounds even if unused
        float gt = data[(bn * TT + step) * FF + t];
        float pv = out[(bn * NSTEP + prev) * FF + t];
        ins[t] = use_gt ? gt : pv;
    }
    __syncthreads();

    float ar = 0.f, ai = 0.f, ah = 0.f;
#pragma unroll 4
    for (int j = 0; j < HH; ++j) {
        float a = sa[j];
        ar = fmaf(a, Whr[j * HH + t], ar);
        ai = fmaf(a, Whi[j * HH + t], ai);
        ah = fmaf(a, Whh[j * HH + t], ah);
    }
    float xr = bir[t], xi = bii[t], xn = bin_[t];
#pragma unroll
    for (int f = 0; f < FF; ++f) {
        float v = ins[f];
        xr = fmaf(v, Wir[f * HH + t], xr);
        xi = fmaf(v, Wii[f * HH + t], xi);
        xn = fmaf(v, Win[f * HH + t], xn);
    }
    float r  = 1.f / (1.f + expf(-(xr + ar)));
    float i  = 1.f / (1.f + expf(-(xi + ai)));
    float nn = tanhf(xn + r * ah);
    float hold = hidden[bn * HH + t];
    float hnew = (1.f - i) * nn + i * hold;
    hidden[bn * HH + t] = hnew;
    sh[t] = hnew;
    __syncthreads();

    float a1 = bo1[t];
#pragma unroll 4
    for (int j = 0; j < HH; ++j) a1 = fmaf(sh[j], Wo1[j * HH + t], a1);
    p1[t] = fmaxf(a1, 0.f);
    __syncthreads();

    float a2 = bo2[t];
#pragma unroll 4
    for (int j = 0; j < HH; ++j) a2 = fmaf(p1[j], Wo2[j * HH + t], a2);
    p2[t] = fmaxf(a2, 0.f);
    __syncthreads();

    if (t < FF) {
        float o = bo3[t];
#pragma unroll 4
        for (int j = 0; j < HH; ++j) o = fmaf(p2[j], Wo3[j * FF + t], o);
        out[(bn * NSTEP + step) * FF + t] = ins[t] + o;
    }

    // ---- next-step node projections from h_new (sh[]) ----
    // rep -> (which = rep>>2: 0=Hs,1=Hr ; k = rep&3); output column = t
    float pacc[8] = {};
    int pbase[8];
#pragma unroll
    for (int rep = 0; rep < 8; ++rep) {
        int k = rep & 3, which = rep >> 2;
        pbase[rep] = (2 * k + which) * HH * HH + t;   // + j*HH per step
    }
#pragma unroll 4
    for (int j = 0; j < HH; ++j) {
        float hj = sh[j];
#pragma unroll
        for (int rep = 0; rep < 8; ++rep)
            pacc[rep] = fmaf(hj, W1[pbase[rep] + j * HH], pacc[rep]);
    }
#pragma unroll
    for (int rep = 0; rep < 8; ++rep) {
        int k = rep & 3, which = rep >> 2;
        if (which == 0) Hs[(bn * KK + k) * HH + t] = pacc[rep];
        else            Hr[(bn * KK + k) * HH + t] = pacc[rep] + b1[k * HH + t];
    }
}

// ---------------------------------------------------------------------------
extern "C" void kernel_launch(void* const* d_in, const int* in_sizes, int n_in,
                              void* d_out, int out_size, void* d_ws, size_t ws_size,
                              hipStream_t stream) {
    const float* data     = (const float*)d_in[0];
    const float* rel_type = (const float*)d_in[1];
    // d_in[2] rel_rec, d_in[3] rel_send: fixed off-diagonal structure, derived analytically
    const int*   ps_ptr   = (const int*)d_in[4];
    const float* W1   = (const float*)d_in[5];
    const float* b1   = (const float*)d_in[6];
    const float* W2   = (const float*)d_in[7];
    const float* b2   = (const float*)d_in[8];
    const float* Whr  = (const float*)d_in[9];
    const float* Whi  = (const float*)d_in[10];
    const float* Whh  = (const float*)d_in[11];
    const float* Wir  = (const float*)d_in[12];
    const float* bir  = (const float*)d_in[13];
    const float* Wii  = (const float*)d_in[14];
    const float* bii  = (const float*)d_in[15];
    const float* Win  = (const float*)d_in[16];
    const float* bin_ = (const float*)d_in[17];
    const float* Wo1  = (const float*)d_in[18];
    const float* bo1  = (const float*)d_in[19];
    const float* Wo2  = (const float*)d_in[20];
    const float* bo2  = (const float*)d_in[21];
    const float* Wo3  = (const float*)d_in[22];
    const float* bo3  = (const float*)d_in[23];

    float* out = (float*)d_out;

    float* ws     = (float*)d_ws;
    float* hidden = ws;                       // B*N*H      = 25600
    float* Hs     = ws + 25600;               // B*N*K*H    = 102400
    float* Hr     = ws + 128000;              // B*N*K*H    = 102400
    float* agg4   = ws + 230400;              // K*B*N*H    = 102400

    k_init<<<400, 256, 0, stream>>>(b1, hidden, agg4, Hs, Hr);

    const int ntile = (EE + TILE_E - 1) / TILE_E;   // 310
    dim3 egrid(ntile, BB, KK);

    for (int step = 0; step < NSTEP; ++step) {
        k_edge<<<egrid, 256, 0, stream>>>(Hs, Hr, W2, b2, rel_type, agg4);
        k_gru_out<<<BB * NN, 128, 0, stream>>>(data, agg4, hidden,
                                               W1, b1,
                                               Whr, Whi, Whh,
                                               Wir, bir, Wii, bii, Win, bin_,
                                               Wo1, bo1, Wo2, bo2, Wo3, bo3,
                                               Hs, Hr, out, ps_ptr, step);
    }
}

// Round 8
// 1223.904 us; speedup vs baseline: 1.0220x; 1.0220x over previous
//
#include <hip/hip_runtime.h>
#include <math.h>

#define BB 2
#define NN 100
#define TT 15
#define FF 6
#define KK 4
#define HH 128
#define EE 9900      // N*(N-1)
#define EPN 99       // edges per receiver (N-1)
#define NSTEP 14     // T-1
#define TILE_E 64

// fast transcendentals: v_exp_f32 + v_rcp_f32 based (HIP intrinsics, ~6 instr)
__device__ __forceinline__ float fast_tanh(float x) {
    // 1 - 2/(1+exp(2x)); x->+inf: exp=inf -> 1; x->-inf: exp=0 -> -1
    float e = __expf(2.0f * x);
    return 1.0f - __fdividef(2.0f, 1.0f + e);
}
__device__ __forceinline__ float fast_sig(float x) {
    return __fdividef(1.0f, 1.0f + __expf(-x));
}

// ---------------------------------------------------------------------------
// K0: one-time init. hidden=0, agg4=0, Hs = 0, Hr = b1.
// ---------------------------------------------------------------------------
__global__ __launch_bounds__(256) void k_init(
    const float* __restrict__ b1,   // [K,H]
    float* __restrict__ hidden,     // [B,N,H]
    float* __restrict__ agg4,       // [K,B,N,H]
    float* __restrict__ Hs,         // [B,N,K,H]
    float* __restrict__ Hr)         // [B,N,K,H]
{
    int i = blockIdx.x * 256 + threadIdx.x;      // < 102400
    if (i < BB * NN * HH) hidden[i] = 0.f;
    agg4[i] = 0.f;
    int k  = (i >> 7) & 3;
    int hh = i & 127;
    Hs[i] = 0.f;
    Hr[i] = b1[k * HH + hh];
}

// ---------------------------------------------------------------------------
// K2: edge messages for ONE edge type k (blockIdx.z), tile of 64 edges.
//   m1 = tanh(Hs[send]+Hr[recv]) staged in LDS (padded rows, 132 floats).
//   W2 read directly from global (L1/L2 resident, lane-broadcast) - no LDS stage.
//   Register blocking: 4 edges x 8 h per thread (256 threads).
// grid: (155, B, K), 256 threads
// ---------------------------------------------------------------------------
__global__ __launch_bounds__(256) void k_edge(
    const float* __restrict__ Hs,        // [B,N,K,H]
    const float* __restrict__ Hr,        // [B,N,K,H]
    const float* __restrict__ W2,        // [K,H,H]
    const float* __restrict__ b2,        // [K,H]
    const float* __restrict__ rel_type,  // [B,E,K]
    float* __restrict__ agg4)            // [K,B,N,H] atomic accum
{
    const int tile = blockIdx.x;
    const int b    = blockIdx.y;
    const int k    = blockIdx.z;
    const int e0   = tile * TILE_E;
    const int t    = threadIdx.x;
    const int hg   = t & 15;        // 16 h-groups of 8
    const int eg   = t >> 4;        // 16 edge-groups, 4 edges each (stride 16)
    const int h0   = hg * 8;

    __shared__ __align__(16) float m1[TILE_E][132];   // padded: bank-spread rows
    __shared__ int s_send[TILE_E], s_recv[TILE_E];

    if (t < TILE_E) {
        int e = e0 + t;
        if (e >= EE) e = EE - 1;
        int r = e / EPN;
        int j = e - r * EPN;
        s_recv[t] = r;
        s_send[t] = j + (j >= r ? 1 : 0);
    }
    __syncthreads();

    // ---- build m1 tile: 64 edges x 128, via float4 (2048 slots, 8/thread) ----
    const float4* Hs4 = (const float4*)Hs;
    const float4* Hr4 = (const float4*)Hr;
#pragma unroll
    for (int rep = 0; rep < 8; ++rep) {
        int idx = rep * 256 + t;
        int el  = idx >> 5;
        int f4  = idx & 31;
        int s   = s_send[el];
        int r   = s_recv[el];
        float4 a = Hs4[((b * NN + s) * KK + k) * 32 + f4];
        float4 c = Hr4[((b * NN + r) * KK + k) * 32 + f4];
        float4 v;
        v.x = fast_tanh(a.x + c.x);
        v.y = fast_tanh(a.y + c.y);
        v.z = fast_tanh(a.z + c.z);
        v.w = fast_tanh(a.w + c.w);
        *(float4*)&m1[el][f4 * 4] = v;
    }
    __syncthreads();

    // ---- this thread's 4 edges (strided by 16) ----
    int   el[4], erecv[4];
    float relw[4];
    const float scale = 1.0f / (KK * FF);
#pragma unroll
    for (int ei = 0; ei < 4; ++ei) {
        int l = eg + 16 * ei;
        el[ei] = l;
        int e = e0 + l;
        bool valid = (e < EE);
        if (!valid) e = EE - 1;
        erecv[ei] = s_recv[l];
        relw[ei]  = valid ? rel_type[(b * EE + e) * KK + k] * scale : 0.f;
    }

    // ---- GEMM: acc[4 edges][8 h] over 128 j; W2 from global, m1 from LDS ----
    const float4* W2f4 = (const float4*)(W2 + k * HH * HH);
    const float4* m1f4 = (const float4*)&m1[0][0];   // row stride 33 float4

    float acc[4][8] = {};
#pragma unroll 2
    for (int js = 0; js < 32; ++js) {        // j-quad index, j = js*4..js*4+3
        float4 wA[4], wB[4];
#pragma unroll
        for (int jj = 0; jj < 4; ++jj) {
            wA[jj] = W2f4[(js * 4 + jj) * 32 + hg * 2];
            wB[jj] = W2f4[(js * 4 + jj) * 32 + hg * 2 + 1];
        }
#pragma unroll
        for (int ei = 0; ei < 4; ++ei) {
            float4 mv = m1f4[el[ei] * 33 + js];
            float* A = acc[ei];
            A[0] = fmaf(mv.x, wA[0].x, fmaf(mv.y, wA[1].x, fmaf(mv.z, wA[2].x, fmaf(mv.w, wA[3].x, A[0]))));
            A[1] = fmaf(mv.x, wA[0].y, fmaf(mv.y, wA[1].y, fmaf(mv.z, wA[2].y, fmaf(mv.w, wA[3].y, A[1]))));
            A[2] = fmaf(mv.x, wA[0].z, fmaf(mv.y, wA[1].z, fmaf(mv.z, wA[2].z, fmaf(mv.w, wA[3].z, A[2]))));
            A[3] = fmaf(mv.x, wA[0].w, fmaf(mv.y, wA[1].w, fmaf(mv.z, wA[2].w, fmaf(mv.w, wA[3].w, A[3]))));
            A[4] = fmaf(mv.x, wB[0].x, fmaf(mv.y, wB[1].x, fmaf(mv.z, wB[2].x, fmaf(mv.w, wB[3].x, A[4]))));
            A[5] = fmaf(mv.x, wB[0].y, fmaf(mv.y, wB[1].y, fmaf(mv.z, wB[2].y, fmaf(mv.w, wB[3].y, A[5]))));
            A[6] = fmaf(mv.x, wB[0].z, fmaf(mv.y, wB[1].z, fmaf(mv.z, wB[2].z, fmaf(mv.w, wB[3].z, A[6]))));
            A[7] = fmaf(mv.x, wB[0].w, fmaf(mv.y, wB[1].w, fmaf(mv.z, wB[2].w, fmaf(mv.w, wB[3].w, A[7]))));
        }
    }

    // ---- epilogue: m2 = tanh(acc + b2), weight, bin by receiver (<=2 per tile) ----
    float b2k[8];
    *(float4*)&b2k[0] = *(const float4*)&b2[k * HH + h0];
    *(float4*)&b2k[4] = *(const float4*)&b2[k * HH + h0 + 4];

    const int rA = s_recv[0];
    const int rB = s_recv[TILE_E - 1];
    float sumA[8] = {}, sumB[8] = {};
#pragma unroll
    for (int ei = 0; ei < 4; ++ei) {
        bool isA = (erecv[ei] == rA);
#pragma unroll
        for (int h = 0; h < 8; ++h) {
            float v = relw[ei] * fast_tanh(acc[ei][h] + b2k[h]);
            if (isA) sumA[h] += v; else sumB[h] += v;
        }
    }

    float* red  = &m1[0][0];   // reuse as [16][128]
    float* aggk = agg4 + ((size_t)(k * BB + b)) * NN * HH;
    __syncthreads();           // all m1 GEMM reads complete
    *(float4*)&red[eg * 128 + h0]     = make_float4(sumA[0], sumA[1], sumA[2], sumA[3]);
    *(float4*)&red[eg * 128 + h0 + 4] = make_float4(sumA[4], sumA[5], sumA[6], sumA[7]);
    __syncthreads();
    if (t < HH) {
        float s = 0.f;
#pragma unroll
        for (int y = 0; y < 16; ++y) s += red[y * 128 + t];
        atomicAdd(&aggk[rA * HH + t], s);
    }
    if (rB != rA) {            // block-uniform
        __syncthreads();       // pass-A reads done
        *(float4*)&red[eg * 128 + h0]     = make_float4(sumB[0], sumB[1], sumB[2], sumB[3]);
        *(float4*)&red[eg * 128 + h0 + 4] = make_float4(sumB[4], sumB[5], sumB[6], sumB[7]);
        __syncthreads();
        if (t < HH) {
            float s = 0.f;
#pragma unroll
            for (int y = 0; y < 16; ++y) s += red[y * 128 + t];
            atomicAdd(&aggk[rB * HH + t], s);
        }
    }
}

// ---------------------------------------------------------------------------
// K3: GRU + output MLP + next-step projections. 256 threads, j-split GEMVs.
// grid: B*N blocks
// ---------------------------------------------------------------------------
__global__ __launch_bounds__(256) void k_gru_out(
    const float* __restrict__ data,   // [B,N,T,F]
    float* __restrict__ agg4,         // [K,B,N,H] read then zeroed
    float* __restrict__ hidden,       // [B,N,H]
    const float* __restrict__ W1,  const float* __restrict__ b1,
    const float* __restrict__ Whr, const float* __restrict__ Whi,
    const float* __restrict__ Whh,
    const float* __restrict__ Wir, const float* __restrict__ bir,
    const float* __restrict__ Wii, const float* __restrict__ bii,
    const float* __restrict__ Win, const float* __restrict__ bin_,
    const float* __restrict__ Wo1, const float* __restrict__ bo1,
    const float* __restrict__ Wo2, const float* __restrict__ bo2,
    const float* __restrict__ Wo3, const float* __restrict__ bo3,
    float* __restrict__ Hs,           // [B,N,K,H]
    float* __restrict__ Hr,           // [B,N,K,H]
    float* __restrict__ out,          // [B,N,NSTEP,F]
    const int* __restrict__ ps_ptr, int step)
{
    const int bn = blockIdx.x;
    const int t  = threadIdx.x;   // 0..255
    const int tt = t & 127;
    const int jh = t >> 7;        // j-half

    __shared__ float sa[HH], sh[HH], p1b[HH], p2b[HH], insb[8];
    __shared__ float gbuf[6][HH];   // 3 gates x 2 halves
    __shared__ float mbuf[2][HH];

    if (t < HH) {
        float s = 0.f;
#pragma unroll
        for (int k = 0; k < KK; ++k) {
            size_t idx = ((size_t)k * BB * NN + bn) * HH + t;
            s += agg4[idx];
            agg4[idx] = 0.f;      // zero for next step
        }
        sa[t] = s;
    }
    if (t < FF) {
        int ps = ps_ptr[0];
        bool use_gt = (ps <= 1) || (step % ps == 0);
        int prev = (step > 0) ? (step - 1) : 0;
        float gt = data[(bn * TT + step) * FF + t];
        float pv = out[(bn * NSTEP + prev) * FF + t];
        insb[t] = use_gt ? gt : pv;
    }
    __syncthreads();

    {   // gate GEMV partials, j-split 2-way
        float pr = 0.f, pi = 0.f, ph = 0.f;
        const int j0 = jh * 64;
#pragma unroll 4
        for (int jj = 0; jj < 64; ++jj) {
            int j = j0 + jj;
            float a = sa[j];
            pr = fmaf(a, Whr[j * HH + tt], pr);
            pi = fmaf(a, Whi[j * HH + tt], pi);
            ph = fmaf(a, Whh[j * HH + tt], ph);
        }
        gbuf[jh][tt] = pr; gbuf[2 + jh][tt] = pi; gbuf[4 + jh][tt] = ph;
    }
    __syncthreads();

    if (t < HH) {
        float ar = gbuf[0][t] + gbuf[1][t];
        float ai = gbuf[2][t] + gbuf[3][t];
        float ah = gbuf[4][t] + gbuf[5][t];
        float xr = bir[t], xi = bii[t], xn = bin_[t];
#pragma unroll
        for (int f = 0; f < FF; ++f) {
            float v = insb[f];
            xr = fmaf(v, Wir[f * HH + t], xr);
            xi = fmaf(v, Wii[f * HH + t], xi);
            xn = fmaf(v, Win[f * HH + t], xn);
        }
        float r  = fast_sig(xr + ar);
        float i  = fast_sig(xi + ai);
        float n  = fast_tanh(xn + r * ah);
        float hnew = (1.f - i) * n + i * hidden[bn * HH + t];
        hidden[bn * HH + t] = hnew;
        sh[t] = hnew;
    }
    __syncthreads();

    {   // MLP1 partial
        float a1 = 0.f;
        const int j0 = jh * 64;
#pragma unroll 4
        for (int jj = 0; jj < 64; ++jj) { int j = j0 + jj; a1 = fmaf(sh[j], Wo1[j * HH + tt], a1); }
        mbuf[jh][tt] = a1;
    }
    __syncthreads();
    if (t < HH) p1b[t] = fmaxf(mbuf[0][t] + mbuf[1][t] + bo1[t], 0.f);
    __syncthreads();
    {   // MLP2 partial
        float a2 = 0.f;
        const int j0 = jh * 64;
#pragma unroll 4
        for (int jj = 0; jj < 64; ++jj) { int j = j0 + jj; a2 = fmaf(p1b[j], Wo2[j * HH + tt], a2); }
        mbuf[jh][tt] = a2;
    }
    __syncthreads();
    if (t < HH) p2b[t] = fmaxf(mbuf[0][t] + mbuf[1][t] + bo2[t], 0.f);
    __syncthreads();

    if (t < FF) {
        float o = bo3[t];
#pragma unroll 4
        for (int j = 0; j < HH; ++j) o = fmaf(p2b[j], Wo3[j * FF + t], o);
        out[(bn * NSTEP + step) * FF + t] = insb[t] + o;
    }

    // ---- next-step projections: thread covers reps {2p+jh}, column tt ----
    float pacc[4] = {0.f, 0.f, 0.f, 0.f};
    int pbase[4];
#pragma unroll
    for (int p = 0; p < 4; ++p) {
        int rep   = 2 * p + jh;
        int plane = 2 * (rep & 3) + (rep >> 2);   // (2k+which)
        pbase[p]  = plane * HH * HH + tt;
    }
#pragma unroll 2
    for (int j = 0; j < HH; ++j) {
        float hj = sh[j];
#pragma unroll
        for (int p = 0; p < 4; ++p)
            pacc[p] = fmaf(hj, W1[pbase[p] + j * HH], pacc[p]);
    }
#pragma unroll
    for (int p = 0; p < 4; ++p) {
        int rep = 2 * p + jh;
        int kk = rep & 3, which = rep >> 2;
        if (which == 0) Hs[(bn * KK + kk) * HH + tt] = pacc[p];
        else            Hr[(bn * KK + kk) * HH + tt] = pacc[p] + b1[kk * HH + tt];
    }
}

// ---------------------------------------------------------------------------
extern "C" void kernel_launch(void* const* d_in, const int* in_sizes, int n_in,
                              void* d_out, int out_size, void* d_ws, size_t ws_size,
                              hipStream_t stream) {
    const float* data     = (const float*)d_in[0];
    const float* rel_type = (const float*)d_in[1];
    // d_in[2] rel_rec, d_in[3] rel_send: fixed off-diagonal structure, derived analytically
    const int*   ps_ptr   = (const int*)d_in[4];
    const float* W1   = (const float*)d_in[5];
    const float* b1   = (const float*)d_in[6];
    const float* W2   = (const float*)d_in[7];
    const float* b2   = (const float*)d_in[8];
    const float* Whr  = (const float*)d_in[9];
    const float* Whi  = (const float*)d_in[10];
    const float* Whh  = (const float*)d_in[11];
    const float* Wir  = (const float*)d_in[12];
    const float* bir  = (const float*)d_in[13];
    const float* Wii  = (const float*)d_in[14];
    const float* bii  = (const float*)d_in[15];
    const float* Win  = (const float*)d_in[16];
    const float* bin_ = (const float*)d_in[17];
    const float* Wo1  = (const float*)d_in[18];
    const float* bo1  = (const float*)d_in[19];
    const float* Wo2  = (const float*)d_in[20];
    const float* bo2  = (const float*)d_in[21];
    const float* Wo3  = (const float*)d_in[22];
    const float* bo3  = (const float*)d_in[23];

    float* out = (float*)d_out;

    float* ws     = (float*)d_ws;
    float* hidden = ws;                       // B*N*H      = 25600
    float* Hs     = ws + 25600;               // B*N*K*H    = 102400
    float* Hr     = ws + 128000;              // B*N*K*H    = 102400
    float* agg4   = ws + 230400;              // K*B*N*H    = 102400

    k_init<<<400, 256, 0, stream>>>(b1, hidden, agg4, Hs, Hr);

    const int ntile = (EE + TILE_E - 1) / TILE_E;   // 155
    dim3 egrid(ntile, BB, KK);

    for (int step = 0; step < NSTEP; ++step) {
        k_edge<<<egrid, 256, 0, stream>>>(Hs, Hr, W2, b2, rel_type, agg4);
        k_gru_out<<<BB * NN, 256, 0, stream>>>(data, agg4, hidden,
                                               W1, b1,
                                               Whr, Whi, Whh,
                                               Wir, bir, Wii, bii, Win, bin_,
                                               Wo1, bo1, Wo2, bo2, Wo3, bo3,
                                               Hs, Hr, out, ps_ptr, step);
    }
}

// Round 9
// 1121.976 us; speedup vs baseline: 1.1149x; 1.0908x over previous
//
#include <hip/hip_runtime.h>
#include <math.h>

#define BB 2
#define NN 100
#define TT 15
#define FF 6
#define KK 4
#define HH 128
#define EE 9900      // N*(N-1)
#define EPN 99       // edges per receiver (N-1)
#define NSTEP 14     // T-1
#define TILE_E 64

// fast transcendentals: v_exp_f32 + v_rcp_f32 based (~6 instr vs ~40 for libm)
__device__ __forceinline__ float fast_tanh(float x) {
    float e = __expf(2.0f * x);
    return 1.0f - __fdividef(2.0f, 1.0f + e);
}
__device__ __forceinline__ float fast_sig(float x) {
    return __fdividef(1.0f, 1.0f + __expf(-x));
}

// ---------------------------------------------------------------------------
// K0: one-time init. hidden=0, agg4=0, Hs = 0, Hr = b1.
// ---------------------------------------------------------------------------
__global__ __launch_bounds__(256) void k_init(
    const float* __restrict__ b1,   // [K,H]
    float* __restrict__ hidden,     // [B,N,H]
    float* __restrict__ agg4,       // [K,B,N,H]
    float* __restrict__ Hs,         // [B,N,K,H]
    float* __restrict__ Hr)         // [B,N,K,H]
{
    int i = blockIdx.x * 256 + threadIdx.x;      // < 102400
    if (i < BB * NN * HH) hidden[i] = 0.f;
    agg4[i] = 0.f;
    int k  = (i >> 7) & 3;
    int hh = i & 127;
    Hs[i] = 0.f;
    Hr[i] = b1[k * HH + hh];
}

// ---------------------------------------------------------------------------
// K2 v3: edge messages for ONE edge type k (blockIdx.z), tile of 64 edges.
//   m1 = tanh(Hs[send]+Hr[recv]) staged in LDS (rows padded to 132).
//   W2[k] staged in LDS in 32-row chunks (16.5 KB), shared by all threads
//   (fixes r5's 1 MB/block redundant L2 traffic -> 64 KB/block).
//   Register blocking: 4 edges x 8 h per thread; both operands from LDS:
//   12 x ds_read_b128 per 128 FMA.
// grid: (155, B, K), 256 threads
// ---------------------------------------------------------------------------
__global__ __launch_bounds__(256) void k_edge(
    const float* __restrict__ Hs,        // [B,N,K,H]
    const float* __restrict__ Hr,        // [B,N,K,H]
    const float* __restrict__ W2,        // [K,H,H]
    const float* __restrict__ b2,        // [K,H]
    const float* __restrict__ rel_type,  // [B,E,K]
    float* __restrict__ agg4)            // [K,B,N,H] atomic accum
{
    const int tile = blockIdx.x;
    const int b    = blockIdx.y;
    const int k    = blockIdx.z;
    const int e0   = tile * TILE_E;
    const int t    = threadIdx.x;
    const int hg   = t & 15;        // 16 h-groups of 8
    const int eg   = t >> 4;        // 16 edge-groups, 4 edges each (stride 16)
    const int h0   = hg * 8;

    __shared__ __align__(16) float m1[TILE_E][132];   // 33.8 KB, padded rows
    __shared__ __align__(16) float w2c[32][132];      // 16.9 KB chunk of W2[k]
    __shared__ int s_send[TILE_E], s_recv[TILE_E];

    if (t < TILE_E) {
        int e = e0 + t;
        if (e >= EE) e = EE - 1;
        int r = e / EPN;
        int j = e - r * EPN;
        s_recv[t] = r;
        s_send[t] = j + (j >= r ? 1 : 0);
    }
    __syncthreads();

    // ---- build m1 tile: 64 edges x 128, via float4 (2048 slots, 8/thread) ----
    const float4* Hs4 = (const float4*)Hs;
    const float4* Hr4 = (const float4*)Hr;
#pragma unroll
    for (int rep = 0; rep < 8; ++rep) {
        int idx = rep * 256 + t;
        int el  = idx >> 5;
        int f4  = idx & 31;
        int s   = s_send[el];
        int r   = s_recv[el];
        float4 a = Hs4[((b * NN + s) * KK + k) * 32 + f4];
        float4 c = Hr4[((b * NN + r) * KK + k) * 32 + f4];
        float4 v;
        v.x = fast_tanh(a.x + c.x);
        v.y = fast_tanh(a.y + c.y);
        v.z = fast_tanh(a.z + c.z);
        v.w = fast_tanh(a.w + c.w);
        *(float4*)&m1[el][f4 * 4] = v;
    }

    // ---- this thread's 4 edges (strided by 16) ----
    int   el[4], erecv[4];
    float relw[4];
    const float scale = 1.0f / (KK * FF);
#pragma unroll
    for (int ei = 0; ei < 4; ++ei) {
        int l = eg + 16 * ei;
        el[ei] = l;
        int e = e0 + l;
        bool valid = (e < EE);
        if (!valid) e = EE - 1;
        erecv[ei] = s_recv[l];
        relw[ei]  = valid ? rel_type[(b * EE + e) * KK + k] * scale : 0.f;
    }

    // ---- GEMM: acc[4][8] over 128 j, W2 staged in LDS 32-row chunks ----
    const float4* W2f4 = (const float4*)(W2 + k * HH * HH);

    float acc[4][8] = {};
    for (int jc = 0; jc < 4; ++jc) {
        __syncthreads();   // m1 ready (jc=0) / prev chunk reads done (jc>0)
        // stage w2c rows [jc*32, jc*32+32): 1024 float4 slots, 4/thread
#pragma unroll
        for (int rep = 0; rep < 4; ++rep) {
            int s   = rep * 256 + t;
            int row = s >> 5;
            int c4  = s & 31;
            *(float4*)&w2c[row][c4 * 4] = W2f4[(jc * 32 + row) * 32 + c4];
        }
        __syncthreads();
#pragma unroll
        for (int js = 0; js < 8; ++js) {     // j-quad within chunk
            float4 wA[4], wB[4];
#pragma unroll
            for (int jj = 0; jj < 4; ++jj) {
                wA[jj] = *(const float4*)&w2c[js * 4 + jj][h0];
                wB[jj] = *(const float4*)&w2c[js * 4 + jj][h0 + 4];
            }
#pragma unroll
            for (int ei = 0; ei < 4; ++ei) {
                float4 mv = *(const float4*)&m1[el[ei]][jc * 32 + js * 4];
                float* A = acc[ei];
                A[0] = fmaf(mv.x, wA[0].x, fmaf(mv.y, wA[1].x, fmaf(mv.z, wA[2].x, fmaf(mv.w, wA[3].x, A[0]))));
                A[1] = fmaf(mv.x, wA[0].y, fmaf(mv.y, wA[1].y, fmaf(mv.z, wA[2].y, fmaf(mv.w, wA[3].y, A[1]))));
                A[2] = fmaf(mv.x, wA[0].z, fmaf(mv.y, wA[1].z, fmaf(mv.z, wA[2].z, fmaf(mv.w, wA[3].z, A[2]))));
                A[3] = fmaf(mv.x, wA[0].w, fmaf(mv.y, wA[1].w, fmaf(mv.z, wA[2].w, fmaf(mv.w, wA[3].w, A[3]))));
                A[4] = fmaf(mv.x, wB[0].x, fmaf(mv.y, wB[1].x, fmaf(mv.z, wB[2].x, fmaf(mv.w, wB[3].x, A[4]))));
                A[5] = fmaf(mv.x, wB[0].y, fmaf(mv.y, wB[1].y, fmaf(mv.z, wB[2].y, fmaf(mv.w, wB[3].y, A[5]))));
                A[6] = fmaf(mv.x, wB[0].z, fmaf(mv.y, wB[1].z, fmaf(mv.z, wB[2].z, fmaf(mv.w, wB[3].z, A[6]))));
                A[7] = fmaf(mv.x, wB[0].w, fmaf(mv.y, wB[1].w, fmaf(mv.z, wB[2].w, fmaf(mv.w, wB[3].w, A[7]))));
            }
        }
    }

    // ---- epilogue: m2 = tanh(acc + b2), weight, bin by receiver (<=2/tile) ----
    float b2k[8];
    *(float4*)&b2k[0] = *(const float4*)&b2[k * HH + h0];
    *(float4*)&b2k[4] = *(const float4*)&b2[k * HH + h0 + 4];

    const int rA = s_recv[0];
    const int rB = s_recv[TILE_E - 1];
    float sumA[8] = {}, sumB[8] = {};
#pragma unroll
    for (int ei = 0; ei < 4; ++ei) {
        bool isA = (erecv[ei] == rA);
#pragma unroll
        for (int h = 0; h < 8; ++h) {
            float v = relw[ei] * fast_tanh(acc[ei][h] + b2k[h]);
            if (isA) sumA[h] += v; else sumB[h] += v;
        }
    }

    float* red  = &m1[0][0];   // reuse as [16][128]
    float* aggk = agg4 + ((size_t)(k * BB + b)) * NN * HH;
    __syncthreads();           // all m1 GEMM reads complete
    *(float4*)&red[eg * 128 + h0]     = make_float4(sumA[0], sumA[1], sumA[2], sumA[3]);
    *(float4*)&red[eg * 128 + h0 + 4] = make_float4(sumA[4], sumA[5], sumA[6], sumA[7]);
    __syncthreads();
    if (t < HH) {
        float s = 0.f;
#pragma unroll
        for (int y = 0; y < 16; ++y) s += red[y * 128 + t];
        atomicAdd(&aggk[rA * HH + t], s);
    }
    if (rB != rA) {            // block-uniform
        __syncthreads();       // pass-A reads done
        *(float4*)&red[eg * 128 + h0]     = make_float4(sumB[0], sumB[1], sumB[2], sumB[3]);
        *(float4*)&red[eg * 128 + h0 + 4] = make_float4(sumB[4], sumB[5], sumB[6], sumB[7]);
        __syncthreads();
        if (t < HH) {
            float s = 0.f;
#pragma unroll
            for (int y = 0; y < 16; ++y) s += red[y * 128 + t];
            atomicAdd(&aggk[rB * HH + t], s);
        }
    }
}

// ---------------------------------------------------------------------------
// K3: GRU + output MLP + next-step projections. 256 threads, j-split GEMVs.
// grid: B*N blocks
// ---------------------------------------------------------------------------
__global__ __launch_bounds__(256) void k_gru_out(
    const float* __restrict__ data,   // [B,N,T,F]
    float* __restrict__ agg4,         // [K,B,N,H] read then zeroed
    float* __restrict__ hidden,       // [B,N,H]
    const float* __restrict__ W1,  const float* __restrict__ b1,
    const float* __restrict__ Whr, const float* __restrict__ Whi,
    const float* __restrict__ Whh,
    const float* __restrict__ Wir, const float* __restrict__ bir,
    const float* __restrict__ Wii, const float* __restrict__ bii,
    const float* __restrict__ Win, const float* __restrict__ bin_,
    const float* __restrict__ Wo1, const float* __restrict__ bo1,
    const float* __restrict__ Wo2, const float* __restrict__ bo2,
    const float* __restrict__ Wo3, const float* __restrict__ bo3,
    float* __restrict__ Hs,           // [B,N,K,H]
    float* __restrict__ Hr,           // [B,N,K,H]
    float* __restrict__ out,          // [B,N,NSTEP,F]
    const int* __restrict__ ps_ptr, int step)
{
    const int bn = blockIdx.x;
    const int t  = threadIdx.x;   // 0..255
    const int tt = t & 127;
    const int jh = t >> 7;        // j-half

    __shared__ float sa[HH], sh[HH], p1b[HH], p2b[HH], insb[8];
    __shared__ float gbuf[6][HH];   // 3 gates x 2 halves
    __shared__ float mbuf[2][HH];

    if (t < HH) {
        float s = 0.f;
#pragma unroll
        for (int k = 0; k < KK; ++k) {
            size_t idx = ((size_t)k * BB * NN + bn) * HH + t;
            s += agg4[idx];
            agg4[idx] = 0.f;      // zero for next step
        }
        sa[t] = s;
    }
    if (t < FF) {
        int ps = ps_ptr[0];
        bool use_gt = (ps <= 1) || (step % ps == 0);
        int prev = (step > 0) ? (step - 1) : 0;
        float gt = data[(bn * TT + step) * FF + t];
        float pv = out[(bn * NSTEP + prev) * FF + t];
        insb[t] = use_gt ? gt : pv;
    }
    __syncthreads();

    {   // gate GEMV partials, j-split 2-way
        float pr = 0.f, pi = 0.f, ph = 0.f;
        const int j0 = jh * 64;
#pragma unroll 4
        for (int jj = 0; jj < 64; ++jj) {
            int j = j0 + jj;
            float a = sa[j];
            pr = fmaf(a, Whr[j * HH + tt], pr);
            pi = fmaf(a, Whi[j * HH + tt], pi);
            ph = fmaf(a, Whh[j * HH + tt], ph);
        }
        gbuf[jh][tt] = pr; gbuf[2 + jh][tt] = pi; gbuf[4 + jh][tt] = ph;
    }
    __syncthreads();

    if (t < HH) {
        float ar = gbuf[0][t] + gbuf[1][t];
        float ai = gbuf[2][t] + gbuf[3][t];
        float ah = gbuf[4][t] + gbuf[5][t];
        float xr = bir[t], xi = bii[t], xn = bin_[t];
#pragma unroll
        for (int f = 0; f < FF; ++f) {
            float v = insb[f];
            xr = fmaf(v, Wir[f * HH + t], xr);
            xi = fmaf(v, Wii[f * HH + t], xi);
            xn = fmaf(v, Win[f * HH + t], xn);
        }
        float r  = fast_sig(xr + ar);
        float i  = fast_sig(xi + ai);
        float n  = fast_tanh(xn + r * ah);
        float hnew = (1.f - i) * n + i * hidden[bn * HH + t];
        hidden[bn * HH + t] = hnew;
        sh[t] = hnew;
    }
    __syncthreads();

    {   // MLP1 partial
        float a1 = 0.f;
        const int j0 = jh * 64;
#pragma unroll 4
        for (int jj = 0; jj < 64; ++jj) { int j = j0 + jj; a1 = fmaf(sh[j], Wo1[j * HH + tt], a1); }
        mbuf[jh][tt] = a1;
    }
    __syncthreads();
    if (t < HH) p1b[t] = fmaxf(mbuf[0][t] + mbuf[1][t] + bo1[t], 0.f);
    __syncthreads();
    {   // MLP2 partial
        float a2 = 0.f;
        const int j0 = jh * 64;
#pragma unroll 4
        for (int jj = 0; jj < 64; ++jj) { int j = j0 + jj; a2 = fmaf(p1b[j], Wo2[j * HH + tt], a2); }
        mbuf[jh][tt] = a2;
    }
    __syncthreads();
    if (t < HH) p2b[t] = fmaxf(mbuf[0][t] + mbuf[1][t] + bo2[t], 0.f);
    __syncthreads();

    if (t < FF) {
        float o = bo3[t];
#pragma unroll 4
        for (int j = 0; j < HH; ++j) o = fmaf(p2b[j], Wo3[j * FF + t], o);
        out[(bn * NSTEP + step) * FF + t] = insb[t] + o;
    }

    // ---- next-step projections: thread covers reps {2p+jh}, column tt ----
    float pacc[4] = {0.f, 0.f, 0.f, 0.f};
    int pbase[4];
#pragma unroll
    for (int p = 0; p < 4; ++p) {
        int rep   = 2 * p + jh;
        int plane = 2 * (rep & 3) + (rep >> 2);   // (2k+which)
        pbase[p]  = plane * HH * HH + tt;
    }
#pragma unroll 2
    for (int j = 0; j < HH; ++j) {
        float hj = sh[j];
#pragma unroll
        for (int p = 0; p < 4; ++p)
            pacc[p] = fmaf(hj, W1[pbase[p] + j * HH], pacc[p]);
    }
#pragma unroll
    for (int p = 0; p < 4; ++p) {
        int rep = 2 * p + jh;
        int kk = rep & 3, which = rep >> 2;
        if (which == 0) Hs[(bn * KK + kk) * HH + tt] = pacc[p];
        else            Hr[(bn * KK + kk) * HH + tt] = pacc[p] + b1[kk * HH + tt];
    }
}

// ---------------------------------------------------------------------------
extern "C" void kernel_launch(void* const* d_in, const int* in_sizes, int n_in,
                              void* d_out, int out_size, void* d_ws, size_t ws_size,
                              hipStream_t stream) {
    const float* data     = (const float*)d_in[0];
    const float* rel_type = (const float*)d_in[1];
    // d_in[2] rel_rec, d_in[3] rel_send: fixed off-diagonal structure, derived analytically
    const int*   ps_ptr   = (const int*)d_in[4];
    const float* W1   = (const float*)d_in[5];
    const float* b1   = (const float*)d_in[6];
    const float* W2   = (const float*)d_in[7];
    const float* b2   = (const float*)d_in[8];
    const float* Whr  = (const float*)d_in[9];
    const float* Whi  = (const float*)d_in[10];
    const float* Whh  = (const float*)d_in[11];
    const float* Wir  = (const float*)d_in[12];
    const float* bir  = (const float*)d_in[13];
    const float* Wii  = (const float*)d_in[14];
    const float* bii  = (const float*)d_in[15];
    const float* Win  = (const float*)d_in[16];
    const float* bin_ = (const float*)d_in[17];
    const float* Wo1  = (const float*)d_in[18];
    const float* bo1  = (const float*)d_in[19];
    const float* Wo2  = (const float*)d_in[20];
    const float* bo2  = (const float*)d_in[21];
    const float* Wo3  = (const float*)d_in[22];
    const float* bo3  = (const float*)d_in[23];

    float* out = (float*)d_out;

    float* ws     = (float*)d_ws;
    float* hidden = ws;                       // B*N*H      = 25600
    float* Hs     = ws + 25600;               // B*N*K*H    = 102400
    float* Hr     = ws + 128000;              // B*N*K*H    = 102400
    float* agg4   = ws + 230400;              // K*B*N*H    = 102400

    k_init<<<400, 256, 0, stream>>>(b1, hidden, agg4, Hs, Hr);

    const int ntile = (EE + TILE_E - 1) / TILE_E;   // 155
    dim3 egrid(ntile, BB, KK);

    for (int step = 0; step < NSTEP; ++step) {
        k_edge<<<egrid, 256, 0, stream>>>(Hs, Hr, W2, b2, rel_type, agg4);
        k_gru_out<<<BB * NN, 256, 0, stream>>>(data, agg4, hidden,
                                               W1, b1,
                                               Whr, Whi, Whh,
                                               Wir, bir, Wii, bii, Win, bin_,
                                               Wo1, bo1, Wo2, bo2, Wo3, bo3,
                                               Hs, Hr, out, ps_ptr, step);
    }
}

// Round 10
// 968.923 us; speedup vs baseline: 1.2910x; 1.1580x over previous
//
#include <hip/hip_runtime.h>
#include <math.h>

#define BB 2
#define NN 100
#define TT 15
#define FF 6
#define KK 4
#define HH 128
#define EE 9900      // N*(N-1)
#define EPN 99       // edges per receiver (N-1)
#define NSTEP 14     // T-1
#define TILE_E 64

// fast transcendentals: v_exp_f32 + v_rcp_f32 based (~6 instr vs ~40 for libm)
__device__ __forceinline__ float fast_tanh(float x) {
    float e = __expf(2.0f * x);
    return 1.0f - __fdividef(2.0f, 1.0f + e);
}
__device__ __forceinline__ float fast_sig(float x) {
    return __fdividef(1.0f, 1.0f + __expf(-x));
}

// ---------------------------------------------------------------------------
// K0: one-time init. hidden=0, agg4=0, Hs = 0, Hr = b1.
// ---------------------------------------------------------------------------
__global__ __launch_bounds__(256) void k_init(
    const float* __restrict__ b1,   // [K,H]
    float* __restrict__ hidden,     // [B,N,H]
    float* __restrict__ agg4,       // [K,B,N,H]
    float* __restrict__ Hs,         // [B,N,K,H]
    float* __restrict__ Hr)         // [B,N,K,H]
{
    int i = blockIdx.x * 256 + threadIdx.x;      // < 102400
    if (i < BB * NN * HH) hidden[i] = 0.f;
    agg4[i] = 0.f;
    int k  = (i >> 7) & 3;
    int hh = i & 127;
    Hs[i] = 0.f;
    Hr[i] = b1[k * HH + hh];
}

// ---------------------------------------------------------------------------
// K2 v4: edge messages for ONE edge type k (blockIdx.z), tile of 64 edges.
//   m1 in LDS (rows padded to 132); W2[k] staged in LDS 32-row chunks.
//   Register blocking 4 edges x 8 h. h-columns per thread are
//   {hg*4..+3} u {64+hg*4..+3} so w2c reads (f4 = hg and 16+hg) cover all
//   8 bank-quads with 2 lanes each (2-way = free) -- fixes r9's 4-way
//   conflict (5.2M/dispatch) from the hg*8 contiguous mapping.
// grid: (155, B, K), 256 threads
// ---------------------------------------------------------------------------
__global__ __launch_bounds__(256) void k_edge(
    const float* __restrict__ Hs,        // [B,N,K,H]
    const float* __restrict__ Hr,        // [B,N,K,H]
    const float* __restrict__ W2,        // [K,H,H]
    const float* __restrict__ b2,        // [K,H]
    const float* __restrict__ rel_type,  // [B,E,K]
    float* __restrict__ agg4)            // [K,B,N,H] atomic accum
{
    const int tile = blockIdx.x;
    const int b    = blockIdx.y;
    const int k    = blockIdx.z;
    const int e0   = tile * TILE_E;
    const int t    = threadIdx.x;
    const int hg   = t & 15;        // 16 h-groups
    const int eg   = t >> 4;        // 16 edge-groups, 4 edges each (stride 16)
    const int cA   = hg * 4;        // first 4-col group
    const int cB   = 64 + hg * 4;   // second 4-col group

    __shared__ __align__(16) float m1[TILE_E][132];   // 33.8 KB, padded rows
    __shared__ __align__(16) float w2c[32][132];      // 16.9 KB chunk of W2[k]
    __shared__ int s_send[TILE_E], s_recv[TILE_E];

    if (t < TILE_E) {
        int e = e0 + t;
        if (e >= EE) e = EE - 1;
        int r = e / EPN;
        int j = e - r * EPN;
        s_recv[t] = r;
        s_send[t] = j + (j >= r ? 1 : 0);
    }
    __syncthreads();

    // ---- build m1 tile: 64 edges x 128, via float4 (2048 slots, 8/thread) ----
    const float4* Hs4 = (const float4*)Hs;
    const float4* Hr4 = (const float4*)Hr;
#pragma unroll
    for (int rep = 0; rep < 8; ++rep) {
        int idx = rep * 256 + t;
        int el  = idx >> 5;
        int f4  = idx & 31;
        int s   = s_send[el];
        int r   = s_recv[el];
        float4 a = Hs4[((b * NN + s) * KK + k) * 32 + f4];
        float4 c = Hr4[((b * NN + r) * KK + k) * 32 + f4];
        float4 v;
        v.x = fast_tanh(a.x + c.x);
        v.y = fast_tanh(a.y + c.y);
        v.z = fast_tanh(a.z + c.z);
        v.w = fast_tanh(a.w + c.w);
        *(float4*)&m1[el][f4 * 4] = v;
    }

    // ---- this thread's 4 edges (strided by 16) ----
    int   el[4], erecv[4];
    float relw[4];
    const float scale = 1.0f / (KK * FF);
#pragma unroll
    for (int ei = 0; ei < 4; ++ei) {
        int l = eg + 16 * ei;
        el[ei] = l;
        int e = e0 + l;
        bool valid = (e < EE);
        if (!valid) e = EE - 1;
        erecv[ei] = s_recv[l];
        relw[ei]  = valid ? rel_type[(b * EE + e) * KK + k] * scale : 0.f;
    }

    // ---- GEMM: acc[4][8] over 128 j, W2 staged in LDS 32-row chunks ----
    const float4* W2f4 = (const float4*)(W2 + k * HH * HH);

    float acc[4][8] = {};
    for (int jc = 0; jc < 4; ++jc) {
        __syncthreads();   // m1 ready (jc=0) / prev chunk reads done (jc>0)
        // stage w2c rows [jc*32, jc*32+32): 1024 float4 slots, 4/thread
#pragma unroll
        for (int rep = 0; rep < 4; ++rep) {
            int s   = rep * 256 + t;
            int row = s >> 5;
            int c4  = s & 31;
            *(float4*)&w2c[row][c4 * 4] = W2f4[(jc * 32 + row) * 32 + c4];
        }
        __syncthreads();
#pragma unroll
        for (int js = 0; js < 8; ++js) {     // j-quad within chunk
            float4 wA[4], wB[4];
#pragma unroll
            for (int jj = 0; jj < 4; ++jj) {
                wA[jj] = *(const float4*)&w2c[js * 4 + jj][cA];
                wB[jj] = *(const float4*)&w2c[js * 4 + jj][cB];
            }
#pragma unroll
            for (int ei = 0; ei < 4; ++ei) {
                float4 mv = *(const float4*)&m1[el[ei]][jc * 32 + js * 4];
                float* A = acc[ei];
                A[0] = fmaf(mv.x, wA[0].x, fmaf(mv.y, wA[1].x, fmaf(mv.z, wA[2].x, fmaf(mv.w, wA[3].x, A[0]))));
                A[1] = fmaf(mv.x, wA[0].y, fmaf(mv.y, wA[1].y, fmaf(mv.z, wA[2].y, fmaf(mv.w, wA[3].y, A[1]))));
                A[2] = fmaf(mv.x, wA[0].z, fmaf(mv.y, wA[1].z, fmaf(mv.z, wA[2].z, fmaf(mv.w, wA[3].z, A[2]))));
                A[3] = fmaf(mv.x, wA[0].w, fmaf(mv.y, wA[1].w, fmaf(mv.z, wA[2].w, fmaf(mv.w, wA[3].w, A[3]))));
                A[4] = fmaf(mv.x, wB[0].x, fmaf(mv.y, wB[1].x, fmaf(mv.z, wB[2].x, fmaf(mv.w, wB[3].x, A[4]))));
                A[5] = fmaf(mv.x, wB[0].y, fmaf(mv.y, wB[1].y, fmaf(mv.z, wB[2].y, fmaf(mv.w, wB[3].y, A[5]))));
                A[6] = fmaf(mv.x, wB[0].z, fmaf(mv.y, wB[1].z, fmaf(mv.z, wB[2].z, fmaf(mv.w, wB[3].z, A[6]))));
                A[7] = fmaf(mv.x, wB[0].w, fmaf(mv.y, wB[1].w, fmaf(mv.z, wB[2].w, fmaf(mv.w, wB[3].w, A[7]))));
            }
        }
    }

    // ---- epilogue: m2 = tanh(acc + b2), weight, bin by receiver (<=2/tile) ----
    float b2k[8];
    *(float4*)&b2k[0] = *(const float4*)&b2[k * HH + cA];
    *(float4*)&b2k[4] = *(const float4*)&b2[k * HH + cB];

    const int rA = s_recv[0];
    const int rB = s_recv[TILE_E - 1];
    float sumA[8] = {}, sumB[8] = {};
#pragma unroll
    for (int ei = 0; ei < 4; ++ei) {
        bool isA = (erecv[ei] == rA);
#pragma unroll
        for (int h = 0; h < 8; ++h) {
            float v = relw[ei] * fast_tanh(acc[ei][h] + b2k[h]);
            if (isA) sumA[h] += v; else sumB[h] += v;
        }
    }

    float* red  = &m1[0][0];   // reuse as [16][128]
    float* aggk = agg4 + ((size_t)(k * BB + b)) * NN * HH;
    __syncthreads();           // all m1 GEMM reads complete
    *(float4*)&red[eg * 128 + cA] = make_float4(sumA[0], sumA[1], sumA[2], sumA[3]);
    *(float4*)&red[eg * 128 + cB] = make_float4(sumA[4], sumA[5], sumA[6], sumA[7]);
    __syncthreads();
    if (t < HH) {
        float s = 0.f;
#pragma unroll
        for (int y = 0; y < 16; ++y) s += red[y * 128 + t];
        atomicAdd(&aggk[rA * HH + t], s);
    }
    if (rB != rA) {            // block-uniform
        __syncthreads();       // pass-A reads done
        *(float4*)&red[eg * 128 + cA] = make_float4(sumB[0], sumB[1], sumB[2], sumB[3]);
        *(float4*)&red[eg * 128 + cB] = make_float4(sumB[4], sumB[5], sumB[6], sumB[7]);
        __syncthreads();
        if (t < HH) {
            float s = 0.f;
#pragma unroll
            for (int y = 0; y < 16; ++y) s += red[y * 128 + t];
            atomicAdd(&aggk[rB * HH + t], s);
        }
    }
}

// ---------------------------------------------------------------------------
// K3 v2: GRU + output MLP + next-step projections. 512 threads (8 waves):
// j-chains split 4-way (gates/MLP, chain 32) and 4-plane x 2-half (proj,
// chain 64); partials reduced through LDS. Doubles resident waves vs r9.
// grid: B*N blocks
// ---------------------------------------------------------------------------
__global__ __launch_bounds__(512) void k_gru_out(
    const float* __restrict__ data,   // [B,N,T,F]
    float* __restrict__ agg4,         // [K,B,N,H] read then zeroed
    float* __restrict__ hidden,       // [B,N,H]
    const float* __restrict__ W1,  const float* __restrict__ b1,
    const float* __restrict__ Whr, const float* __restrict__ Whi,
    const float* __restrict__ Whh,
    const float* __restrict__ Wir, const float* __restrict__ bir,
    const float* __restrict__ Wii, const float* __restrict__ bii,
    const float* __restrict__ Win, const float* __restrict__ bin_,
    const float* __restrict__ Wo1, const float* __restrict__ bo1,
    const float* __restrict__ Wo2, const float* __restrict__ bo2,
    const float* __restrict__ Wo3, const float* __restrict__ bo3,
    float* __restrict__ Hs,           // [B,N,K,H]
    float* __restrict__ Hr,           // [B,N,K,H]
    float* __restrict__ out,          // [B,N,NSTEP,F]
    const int* __restrict__ ps_ptr, int step)
{
    const int bn = blockIdx.x;
    const int t  = threadIdx.x;   // 0..511
    const int tt = t & 127;       // output column
    const int q  = t >> 7;        // 0..3 j-quarter / task group

    __shared__ float sa[HH], sh[HH], p1b[HH], p2b[HH], insb[8];
    __shared__ float ap[4][HH];      // agg partials (per k)
    __shared__ float gp[3][4][HH];   // gate partials
    __shared__ float mp[4][HH];      // mlp partials
    __shared__ float pp[16][HH];     // proj partials (plane*2+half)

    {   // agg read + zero: one element per thread (k=q, col=tt)
        size_t idx = ((size_t)q * BB * NN + bn) * HH + tt;
        ap[q][tt] = agg4[idx];
        agg4[idx] = 0.f;
    }
    if (t < FF) {
        int ps = ps_ptr[0];
        bool use_gt = (ps <= 1) || (step % ps == 0);
        int prev = (step > 0) ? (step - 1) : 0;
        float gt = data[(bn * TT + step) * FF + t];
        float pv = out[(bn * NSTEP + prev) * FF + t];
        insb[t] = use_gt ? gt : pv;
    }
    __syncthreads();
    if (t < HH) sa[t] = ap[0][t] + ap[1][t] + ap[2][t] + ap[3][t];
    __syncthreads();

    {   // gate GEMV partials: 3 gates, chain 32
        const int j0 = q * 32;
        float pr = 0.f, pi = 0.f, ph = 0.f;
#pragma unroll 8
        for (int jj = 0; jj < 32; ++jj) {
            int j = j0 + jj;
            float a = sa[j];
            pr = fmaf(a, Whr[j * HH + tt], pr);
            pi = fmaf(a, Whi[j * HH + tt], pi);
            ph = fmaf(a, Whh[j * HH + tt], ph);
        }
        gp[0][q][tt] = pr; gp[1][q][tt] = pi; gp[2][q][tt] = ph;
    }
    __syncthreads();

    if (t < HH) {
        float ar = gp[0][0][t] + gp[0][1][t] + gp[0][2][t] + gp[0][3][t];
        float ai = gp[1][0][t] + gp[1][1][t] + gp[1][2][t] + gp[1][3][t];
        float ah = gp[2][0][t] + gp[2][1][t] + gp[2][2][t] + gp[2][3][t];
        float xr = bir[t], xi = bii[t], xn = bin_[t];
#pragma unroll
        for (int f = 0; f < FF; ++f) {
            float v = insb[f];
            xr = fmaf(v, Wir[f * HH + t], xr);
            xi = fmaf(v, Wii[f * HH + t], xi);
            xn = fmaf(v, Win[f * HH + t], xn);
        }
        float r  = fast_sig(xr + ar);
        float i  = fast_sig(xi + ai);
        float n  = fast_tanh(xn + r * ah);
        float hnew = (1.f - i) * n + i * hidden[bn * HH + t];
        hidden[bn * HH + t] = hnew;
        sh[t] = hnew;
    }
    __syncthreads();

    {   // MLP1 partial: chain 32
        const int j0 = q * 32;
        float a1 = 0.f;
#pragma unroll 8
        for (int jj = 0; jj < 32; ++jj) { int j = j0 + jj; a1 = fmaf(sh[j], Wo1[j * HH + tt], a1); }
        mp[q][tt] = a1;
    }
    __syncthreads();
    if (t < HH) p1b[t] = fmaxf(mp[0][t] + mp[1][t] + mp[2][t] + mp[3][t] + bo1[t], 0.f);
    __syncthreads();
    {   // MLP2 partial: chain 32
        const int j0 = q * 32;
        float a2 = 0.f;
#pragma unroll 8
        for (int jj = 0; jj < 32; ++jj) { int j = j0 + jj; a2 = fmaf(p1b[j], Wo2[j * HH + tt], a2); }
        mp[q][tt] = a2;
    }
    __syncthreads();
    if (t < HH) p2b[t] = fmaxf(mp[0][t] + mp[1][t] + mp[2][t] + mp[3][t] + bo2[t], 0.f);
    __syncthreads();

    if (t < FF) {
        float o = bo3[t];
#pragma unroll 4
        for (int j = 0; j < HH; ++j) o = fmaf(p2b[j], Wo3[j * FF + t], o);
        out[(bn * NSTEP + step) * FF + t] = insb[t] + o;
    }

    {   // next-step projections: 4 (plane,half) combos per thread, chain 64
#pragma unroll
        for (int i = 0; i < 4; ++i) {
            int c     = 4 * q + i;       // 0..15
            int plane = c >> 1;          // 0..7  (= 2k+which)
            int half  = c & 1;
            const float* Wp = W1 + (size_t)plane * HH * HH + tt;
            const int j0 = half * 64;
            float acc = 0.f;
#pragma unroll 8
            for (int jj = 0; jj < 64; ++jj) {
                int j = j0 + jj;
                acc = fmaf(sh[j], Wp[j * HH], acc);
            }
            pp[c][tt] = acc;
        }
    }
    __syncthreads();
    for (int o = t; o < 1024; o += 512) {
        int plane = o >> 7;          // 0..7
        int col   = o & 127;
        float v = pp[plane * 2][col] + pp[plane * 2 + 1][col];
        int kk = plane >> 1, which = plane & 1;
        if (which == 0) Hs[(bn * KK + kk) * HH + col] = v;
        else            Hr[(bn * KK + kk) * HH + col] = v + b1[kk * HH + col];
    }
}

// ---------------------------------------------------------------------------
extern "C" void kernel_launch(void* const* d_in, const int* in_sizes, int n_in,
                              void* d_out, int out_size, void* d_ws, size_t ws_size,
                              hipStream_t stream) {
    const float* data     = (const float*)d_in[0];
    const float* rel_type = (const float*)d_in[1];
    // d_in[2] rel_rec, d_in[3] rel_send: fixed off-diagonal structure, derived analytically
    const int*   ps_ptr   = (const int*)d_in[4];
    const float* W1   = (const float*)d_in[5];
    const float* b1   = (const float*)d_in[6];
    const float* W2   = (const float*)d_in[7];
    const float* b2   = (const float*)d_in[8];
    const float* Whr  = (const float*)d_in[9];
    const float* Whi  = (const float*)d_in[10];
    const float* Whh  = (const float*)d_in[11];
    const float* Wir  = (const float*)d_in[12];
    const float* bir  = (const float*)d_in[13];
    const float* Wii  = (const float*)d_in[14];
    const float* bii  = (const float*)d_in[15];
    const float* Win  = (const float*)d_in[16];
    const float* bin_ = (const float*)d_in[17];
    const float* Wo1  = (const float*)d_in[18];
    const float* bo1  = (const float*)d_in[19];
    const float* Wo2  = (const float*)d_in[20];
    const float* bo2  = (const float*)d_in[21];
    const float* Wo3  = (const float*)d_in[22];
    const float* bo3  = (const float*)d_in[23];

    float* out = (float*)d_out;

    float* ws     = (float*)d_ws;
    float* hidden = ws;                       // B*N*H      = 25600
    float* Hs     = ws + 25600;               // B*N*K*H    = 102400
    float* Hr     = ws + 128000;              // B*N*K*H    = 102400
    float* agg4   = ws + 230400;              // K*B*N*H    = 102400

    k_init<<<400, 256, 0, stream>>>(b1, hidden, agg4, Hs, Hr);

    const int ntile = (EE + TILE_E - 1) / TILE_E;   // 155
    dim3 egrid(ntile, BB, KK);

    for (int step = 0; step < NSTEP; ++step) {
        k_edge<<<egrid, 256, 0, stream>>>(Hs, Hr, W2, b2, rel_type, agg4);
        k_gru_out<<<BB * NN, 512, 0, stream>>>(data, agg4, hidden,
                                               W1, b1,
                                               Whr, Whi, Whh,
                                               Wir, bir, Wii, bii, Win, bin_,
                                               Wo1, bo1, Wo2, bo2, Wo3, bo3,
                                               Hs, Hr, out, ps_ptr, step);
    }
}